// Round 7
// baseline (117.328 us; speedup 1.0000x reference)
//
#include <hip/hip_runtime.h>
#include <hip/hip_bf16.h>
#include <math.h>

typedef __attribute__((ext_vector_type(4)))  float f32x4;
typedef __attribute__((ext_vector_type(16))) float f32x16;
typedef __attribute__((ext_vector_type(8)))  short bf16x8;
typedef __attribute__((ext_vector_type(4)))  int   i32x4;

#define NB 2
#define NH 12
#define NS 2048
#define ND 64
#define NKER 9
#define BH (NB*NH)
#define BHS (NB*NH*NS)

using bf16 = __hip_bfloat16;

__device__ __forceinline__ f32x16 mfma32(bf16x8 a, bf16x8 b, f32x16 c) {
  return __builtin_amdgcn_mfma_f32_32x32x16_bf16(a, b, c, 0, 0, 0);
}

// RNE float->bf16 (finite inputs).
__device__ __forceinline__ unsigned short bf16rne(float f) {
  unsigned u = __builtin_bit_cast(unsigned, f);
  u += 0x7FFFu + ((u >> 16) & 1u);
  return (unsigned short)(u >> 16);
}

// packed RNE: d[15:0]=bf16(lo), d[31:16]=bf16(hi)
__device__ __forceinline__ int cvtpk_bf16(float lo, float hi) {
  int d;
  asm("v_cvt_pk_bf16_f32 %0, %1, %2" : "=v"(d) : "v"(lo), "v"(hi));
  return d;
}

// ---------------------------------------------------------------------------
// prep: per (bh, 64-seq tile): depthwise conv -> out, masked V^T bf16 -> Vmt,
// and L2-normalized K -> Kn. One pass over K/V.
// ---------------------------------------------------------------------------
__global__ __launch_bounds__(256) void prep(
    const float* __restrict__ K, const float* __restrict__ V,
    const float* __restrict__ mask, const float* __restrict__ cw,
    float* __restrict__ out, bf16* __restrict__ Kn, bf16* __restrict__ Vmt) {
  __shared__ float tile[72][68];
  __shared__ float wsm[NKER];
  int bh = blockIdx.y, b = bh / NH, h = bh % NH;
  int s0 = blockIdx.x * 64;
  int tid = threadIdx.x;
  if (tid < NKER) wsm[tid] = cw[h * NKER + tid];

  int r  = tid >> 2;
  int c0 = (tid & 3) * 16;

  // --- K-normalize rows
  {
    const float* Kr = K + ((size_t)bh * NS + s0 + r) * ND + c0;
    float v[16]; float ss = 0.f;
    #pragma unroll
    for (int j = 0; j < 16; ++j) { v[j] = Kr[j]; ss += v[j] * v[j]; }
    ss += __shfl_xor(ss, 1); ss += __shfl_xor(ss, 2);
    float sc = rsqrtf(fmaxf(ss, 1e-24f));
    bf16x8 o0, o1;
    #pragma unroll
    for (int j = 0; j < 8; ++j) {
      o0[j] = (short)bf16rne(v[j] * sc);
      o1[j] = (short)bf16rne(v[8 + j] * sc);
    }
    bf16* dst = Kn + ((size_t)bh * NS + s0 + r) * ND + c0;
    *(bf16x8*)dst = o0; *(bf16x8*)(dst + 8) = o1;
  }

  // --- masked V halo tile
  #pragma unroll
  for (int pass = 0; pass < 2; ++pass) {
    int rr = r + pass * 64;
    if (pass == 0 || tid < 32) {
      int gs = s0 - NKER / 2 + rr;
      bool ok = (gs >= 0 && gs < NS);
      float m = ok ? mask[b * NS + gs] : 0.f;
      #pragma unroll
      for (int j = 0; j < 16; ++j)
        tile[rr][c0 + j] = ok ? V[((size_t)bh * NS + gs) * ND + c0 + j] * m : 0.f;
    }
  }
  __syncthreads();

  // --- conv
  {
    float acc[16];
    #pragma unroll
    for (int j = 0; j < 16; ++j) acc[j] = 0.f;
    #pragma unroll
    for (int k = 0; k < NKER; ++k) {
      float w = wsm[k];
      #pragma unroll
      for (int j = 0; j < 16; ++j) acc[j] += tile[r + k][c0 + j] * w;
    }
    float* dst = out + ((size_t)bh * NS + s0 + r) * ND + c0;
    #pragma unroll
    for (int j = 0; j < 16; ++j) dst[j] = acc[j];
  }
  // --- V^T (masked, bf16)
  {
    bf16x8 o0, o1;
    #pragma unroll
    for (int j = 0; j < 8; ++j) {
      o0[j] = (short)bf16rne(tile[NKER / 2 + c0 + j][r]);
      o1[j] = (short)bf16rne(tile[NKER / 2 + c0 + 8 + j][r]);
    }
    bf16* dst = Vmt + (size_t)bh * ND * NS + (size_t)r * NS + s0 + c0;
    *(bf16x8*)dst = o0; *(bf16x8*)(dst + 8) = o1;
  }
}

// ---------------------------------------------------------------------------
// Fused YOSO attention, LDS-free main loop. Block = 32 q-rows, 4 waves =
// 4 key-quarters (kh). Wave = 32q x 32k MFMA tiles, 16 tiles of its 512-key
// range. K/V fragments read directly from global (L2-resident: 512 KB per bh;
// XCD-swizzled block mapping keeps 3 bh per XCD's L2). Swapped QK^T
// (St = K x Q) puts P-row q=ql lane-local; P->A-fragments built in-register
// via v_cvt_pk_bf16_f32 + half-wave exchange (no P LDS, no main-loop
// barriers). Epilogue: kh-partials combined via LDS, mask, L2-norm, += out.
// ---------------------------------------------------------------------------
__global__ __launch_bounds__(256) void yoso_attn(
    const float* __restrict__ Q, const bf16* __restrict__ Kn,
    const bf16* __restrict__ Vmt, const float* __restrict__ mask,
    float* __restrict__ out) {
  __shared__ float cmb[3][32][64];   // 24 KB, epilogue only

  int tid  = threadIdx.x;
  int kh   = tid >> 6;          // wave = key-quarter
  int lane = tid & 63;
  int ql   = lane & 31;
  int c    = lane >> 5;

  // XCD-aware decode: bx&7 stays on one XCD (round-robin dispatch) -> each
  // XCD sees bh in {x, x+8, x+16}: 1.5 MB K/V working set per XCD L2.
  int bx = blockIdx.x;
  int bh = ((bx >> 3) / 64) * 8 + (bx & 7);
  int qg = (bx >> 3) & 63;
  int b  = bh / NH;
  int q0 = qg * 32;

  const bf16* Kbh = Kn  + (size_t)bh * NS * ND;
  const bf16* Vbh = Vmt + (size_t)bh * ND * NS;

  // ---- Q load + L2-normalize + fragments (B-operand of QK^T)
  bf16x8 aq[4];
  {
    int qrow = q0 + ql;
    const float* Qr = Q + ((size_t)bh * NS + qrow) * ND;
    float qv[32]; float ss = 0.f;
    #pragma unroll
    for (int t = 0; t < 4; ++t) {
      f32x4 a0 = *(const f32x4*)(Qr + t * 16 + c * 8);
      f32x4 a1 = *(const f32x4*)(Qr + t * 16 + c * 8 + 4);
      #pragma unroll
      for (int j = 0; j < 4; ++j) {
        qv[t * 8 + j] = a0[j]; qv[t * 8 + 4 + j] = a1[j];
        ss += a0[j] * a0[j] + a1[j] * a1[j];
      }
    }
    ss += __shfl_xor(ss, 32);
    float sc = rsqrtf(fmaxf(ss, 1e-24f));
    #pragma unroll
    for (int t = 0; t < 4; ++t)
      #pragma unroll
      for (int j = 0; j < 8; ++j)
        aq[t][j] = (short)bf16rne(qv[t * 8 + j] * sc);
  }

  f32x16 xa0{}, xa1{};

  // per-lane global fragment bases
  const char* kp  = (const char*)Kbh + (size_t)(kh * 512 + ql) * 128 + c * 16;
  const char* vp0 = (const char*)Vbh + (size_t)ql * (NS * 2) + kh * 1024 + c * 16;
  const char* vp1 = vp0 + (size_t)32 * (NS * 2);

  #pragma unroll 1
  for (int kt = 0; kt < 16; ++kt) {
    const char* kpt  = kp + (size_t)kt * (32 * 128);
    const char* vpt0 = vp0 + kt * 64;
    const char* vpt1 = vp1 + kt * 64;
    bf16x8 ak0 = *(const bf16x8*)(kpt);
    bf16x8 ak1 = *(const bf16x8*)(kpt + 32);
    bf16x8 ak2 = *(const bf16x8*)(kpt + 64);
    bf16x8 ak3 = *(const bf16x8*)(kpt + 96);
    bf16x8 bv00 = *(const bf16x8*)(vpt0);
    bf16x8 bv01 = *(const bf16x8*)(vpt0 + 32);
    bf16x8 bv10 = *(const bf16x8*)(vpt1);
    bf16x8 bv11 = *(const bf16x8*)(vpt1 + 32);

    // swapped QK^T: St[key][q], lane: col q=ql, reg r -> key (r&3)+8(r>>2)+4c
    f32x16 s{};
    s = mfma32(ak0, aq[0], s);
    s = mfma32(ak1, aq[1], s);
    s = mfma32(ak2, aq[2], s);
    s = mfma32(ak3, aq[3], s);

    // transform + pack in quads (keeps live range small)
    int pk[8];
    #pragma unroll
    for (int g = 0; g < 4; ++g) {
      float wq[4];
      #pragma unroll
      for (int j = 0; j < 4; ++j) {
        float x = s[g * 4 + j];
        float a = fminf(fabsf(x), 0.999999f);
        float sq = __builtin_amdgcn_sqrtf(1.0f - a);
        float p = fmaf(fmaf(fmaf(-0.005961377f, a, 0.02363857f), a,
                            -0.06751758f), a, 0.49998939f);   // acos/pi poly
        float u = sq * p;
        float t1 = (x >= 0.0f) ? (1.0f - u) : u;
        float t2 = t1 * t1, t4 = t2 * t2;
        wq[j] = t4 * t4;
      }
      pk[g * 2]     = cvtpk_bf16(wq[0], wq[1]);
      pk[g * 2 + 1] = cvtpk_bf16(wq[2], wq[3]);
    }
    // half-wave exchange: build A-fragments P[q=ql][k] (k = 16*ks + 8c + j)
    int xpk[8];
    #pragma unroll
    for (int i = 0; i < 8; ++i) xpk[i] = __shfl_xor(pk[i], 32);
    i32x4 pa0i = c ? (i32x4){xpk[2], xpk[3], pk[2], pk[3]}
                   : (i32x4){pk[0], pk[1], xpk[0], xpk[1]};
    i32x4 pa1i = c ? (i32x4){xpk[6], xpk[7], pk[6], pk[7]}
                   : (i32x4){pk[4], pk[5], xpk[4], xpk[5]};
    bf16x8 pa0 = __builtin_bit_cast(bf16x8, pa0i);
    bf16x8 pa1 = __builtin_bit_cast(bf16x8, pa1i);

    // PV: X[q][d] += P * V^T
    xa0 = mfma32(pa0, bv00, xa0);
    xa1 = mfma32(pa0, bv10, xa1);
    xa0 = mfma32(pa1, bv01, xa0);
    xa1 = mfma32(pa1, bv11, xa1);
  }

  // ---- epilogue: combine 4 key-quarters, mask, L2-normalize, accumulate
  if (kh != 0) {
    #pragma unroll
    for (int r = 0; r < 16; ++r) {
      int qrow = (r & 3) + 8 * (r >> 2) + 4 * c;
      cmb[kh - 1][qrow][ql]      = xa0[r];
      cmb[kh - 1][qrow][32 + ql] = xa1[r];
    }
  }
  __syncthreads();
  if (kh == 0) {
    #pragma unroll
    for (int r = 0; r < 16; ++r) {
      int qrow = (r & 3) + 8 * (r >> 2) + 4 * c;
      int row  = q0 + qrow;
      float m  = mask[b * NS + row];
      float x0 = (xa0[r] + cmb[0][qrow][ql] + cmb[1][qrow][ql] + cmb[2][qrow][ql]) * m;
      float x1 = (xa1[r] + cmb[0][qrow][32 + ql] + cmb[1][qrow][32 + ql] + cmb[2][qrow][32 + ql]) * m;
      float s2 = x0 * x0 + x1 * x1;
      #pragma unroll
      for (int mm = 1; mm < 32; mm <<= 1) s2 += __shfl_xor(s2, mm);
      float sc = rsqrtf(fmaxf(s2, 1e-24f));
      size_t base = ((size_t)bh * NS + row) * ND;
      out[base + ql]      += x0 * sc;
      out[base + 32 + ql] += x1 * sc;
    }
  }
}

// ---------------------------------------------------------------------------
extern "C" void kernel_launch(void* const* d_in, const int* in_sizes, int n_in,
                              void* d_out, int out_size, void* d_ws, size_t ws_size,
                              hipStream_t stream) {
  const float* Q    = (const float*)d_in[0];
  const float* K    = (const float*)d_in[1];
  const float* V    = (const float*)d_in[2];
  const float* mask = (const float*)d_in[3];
  const float* cw   = (const float*)d_in[4];
  float* out = (float*)d_out;

  bf16* Kn  = (bf16*)d_ws;
  bf16* Vmt = Kn + (size_t)BHS * ND;

  prep<<<dim3(NS / 64, BH), 256, 0, stream>>>(K, V, mask, cw, out, Kn, Vmt);
  yoso_attn<<<(NS / 32) * BH, 256, 0, stream>>>(Q, Kn, Vmt, mask, out);
}

// Round 8
// 85.529 us; speedup vs baseline: 1.3718x; 1.3718x over previous
//
#include <hip/hip_runtime.h>
#include <hip/hip_bf16.h>
#include <math.h>

typedef __attribute__((ext_vector_type(4)))  float f32x4;
typedef __attribute__((ext_vector_type(16))) float f32x16;
typedef __attribute__((ext_vector_type(8)))  short bf16x8;
typedef __attribute__((ext_vector_type(4)))  int   i32x4;

#define NB 2
#define NH 12
#define NS 2048
#define ND 64
#define NKER 9
#define BH (NB*NH)
#define BHS (NB*NH*NS)
#define TK 128            // keys per tile
#define NT (NS/TK)        // 16 tiles

using bf16 = __hip_bfloat16;

__device__ __forceinline__ f32x16 mfma32(bf16x8 a, bf16x8 b, f32x16 c) {
  return __builtin_amdgcn_mfma_f32_32x32x16_bf16(a, b, c, 0, 0, 0);
}

// RNE float->bf16 (finite inputs).
__device__ __forceinline__ unsigned short bf16rne(float f) {
  unsigned u = __builtin_bit_cast(unsigned, f);
  u += 0x7FFFu + ((u >> 16) & 1u);
  return (unsigned short)(u >> 16);
}

// packed RNE: d[15:0]=bf16(lo), d[31:16]=bf16(hi)
__device__ __forceinline__ int cvtpk_bf16(float lo, float hi) {
  int d;
  asm("v_cvt_pk_bf16_f32 %0, %1, %2" : "=v"(d) : "v"(lo), "v"(hi));
  return d;
}

// ---------------------------------------------------------------------------
// prep: per (bh, 64-seq tile): depthwise conv -> out, masked V^T bf16 -> Vmt,
// and L2-normalized K -> Kn. One pass over K/V.
// ---------------------------------------------------------------------------
__global__ __launch_bounds__(256) void prep(
    const float* __restrict__ K, const float* __restrict__ V,
    const float* __restrict__ mask, const float* __restrict__ cw,
    float* __restrict__ out, bf16* __restrict__ Kn, bf16* __restrict__ Vmt) {
  __shared__ float tile[72][68];
  __shared__ float wsm[NKER];
  int bh = blockIdx.y, b = bh / NH, h = bh % NH;
  int s0 = blockIdx.x * 64;
  int tid = threadIdx.x;
  if (tid < NKER) wsm[tid] = cw[h * NKER + tid];

  int r  = tid >> 2;
  int c0 = (tid & 3) * 16;

  // --- K-normalize rows
  {
    const float* Kr = K + ((size_t)bh * NS + s0 + r) * ND + c0;
    float v[16]; float ss = 0.f;
    #pragma unroll
    for (int j = 0; j < 16; ++j) { v[j] = Kr[j]; ss += v[j] * v[j]; }
    ss += __shfl_xor(ss, 1); ss += __shfl_xor(ss, 2);
    float sc = rsqrtf(fmaxf(ss, 1e-24f));
    bf16x8 o0, o1;
    #pragma unroll
    for (int j = 0; j < 8; ++j) {
      o0[j] = (short)bf16rne(v[j] * sc);
      o1[j] = (short)bf16rne(v[8 + j] * sc);
    }
    bf16* dst = Kn + ((size_t)bh * NS + s0 + r) * ND + c0;
    *(bf16x8*)dst = o0; *(bf16x8*)(dst + 8) = o1;
  }

  // --- masked V halo tile
  #pragma unroll
  for (int pass = 0; pass < 2; ++pass) {
    int rr = r + pass * 64;
    if (pass == 0 || tid < 32) {
      int gs = s0 - NKER / 2 + rr;
      bool ok = (gs >= 0 && gs < NS);
      float m = ok ? mask[b * NS + gs] : 0.f;
      #pragma unroll
      for (int j = 0; j < 16; ++j)
        tile[rr][c0 + j] = ok ? V[((size_t)bh * NS + gs) * ND + c0 + j] * m : 0.f;
    }
  }
  __syncthreads();

  // --- conv
  {
    float acc[16];
    #pragma unroll
    for (int j = 0; j < 16; ++j) acc[j] = 0.f;
    #pragma unroll
    for (int k = 0; k < NKER; ++k) {
      float w = wsm[k];
      #pragma unroll
      for (int j = 0; j < 16; ++j) acc[j] += tile[r + k][c0 + j] * w;
    }
    float* dst = out + ((size_t)bh * NS + s0 + r) * ND + c0;
    #pragma unroll
    for (int j = 0; j < 16; ++j) dst[j] = acc[j];
  }
  // --- V^T (masked, bf16)
  {
    bf16x8 o0, o1;
    #pragma unroll
    for (int j = 0; j < 8; ++j) {
      o0[j] = (short)bf16rne(tile[NKER / 2 + c0 + j][r]);
      o1[j] = (short)bf16rne(tile[NKER / 2 + c0 + 8 + j][r]);
    }
    bf16* dst = Vmt + (size_t)bh * ND * NS + (size_t)r * NS + s0 + c0;
    *(bf16x8*)dst = o0; *(bf16x8*)(dst + 8) = o1;
  }
}

// ---------------------------------------------------------------------------
// Fused YOSO attention. Block = 64 q-rows x 128-key tiles; 8 waves =
// 2 qsub (32q) x 4 kh (32k). K/V LDS double-buffered (2 x 32 KB), reg-staged,
// 1 barrier/tile. Swapped QK^T (St = K x Q) -> P lane-local -> A-fragments
// in-register (cvt_pk + half-wave shfl); no P LDS. XCD-aware block mapping:
// 3 bh per XCD -> K/V L2-resident. Epilogue: kh-partials via LDS, mask,
// L2-norm, += out. LDS tiles swizzled byte ^= (row&7)<<4.
// ---------------------------------------------------------------------------
__global__ __launch_bounds__(512) void yoso_attn(
    const float* __restrict__ Q, const bf16* __restrict__ Kn,
    const bf16* __restrict__ Vmt, const float* __restrict__ mask,
    float* __restrict__ out) {
  __shared__ __align__(16) char lds[64 * 1024];
  // buf b at b*32768: K [128 keys][128B] at +0, V^T [64 d][256B] at +16384.

  int tid  = threadIdx.x;
  int wave = tid >> 6;
  int lane = tid & 63;
  int ql   = lane & 31;
  int c    = lane >> 5;
  int qsub = wave >> 2;
  int kh   = wave & 3;

  // XCD-aware decode: bx&7 = XCD; each XCD serves bh in {x, x+8, x+16}.
  int bx  = blockIdx.x;
  int idx = bx >> 3;                 // 0..95
  int bh  = (bx & 7) + 8 * (idx >> 5);
  int qg  = idx & 31;
  int b   = bh / NH;
  int q0  = qg * 64;

  const bf16* Kbh = Kn  + (size_t)bh * NS * ND;
  const bf16* Vbh = Vmt + (size_t)bh * ND * NS;

  // ---- Q load + L2-normalize + fragments (B-operand of swapped QK^T)
  bf16x8 aq[4];
  {
    int qrow = q0 + qsub * 32 + ql;
    const float* Qr = Q + ((size_t)bh * NS + qrow) * ND;
    float qv[32]; float ss = 0.f;
    #pragma unroll
    for (int t = 0; t < 4; ++t) {
      f32x4 a0 = *(const f32x4*)(Qr + t * 16 + c * 8);
      f32x4 a1 = *(const f32x4*)(Qr + t * 16 + c * 8 + 4);
      #pragma unroll
      for (int j = 0; j < 4; ++j) {
        qv[t * 8 + j] = a0[j]; qv[t * 8 + 4 + j] = a1[j];
        ss += a0[j] * a0[j] + a1[j] * a1[j];
      }
    }
    ss += __shfl_xor(ss, 32);
    float sc = rsqrtf(fmaxf(ss, 1e-24f));
    #pragma unroll
    for (int t = 0; t < 4; ++t)
      #pragma unroll
      for (int j = 0; j < 8; ++j)
        aq[t][j] = (short)bf16rne(qv[t * 8 + j] * sc);
  }

  f32x16 xa0{}, xa1{};

  // ---- staging addresses: 512 threads, 2 K-chunks + 2 V-chunks (16B) each.
  // K chunk c: krow=c>>3, kcol=(c&7)*16.  V chunk c: vrow=c>>4, vcol=(c&15)*16.
  int kr0r = tid >> 3,          kr0c = (tid & 7) * 16;
  int kr1r = (tid + 512) >> 3,  kr1c = kr0c;
  int vr0r = tid >> 4,          vr0c = (tid & 15) * 16;
  int vr1r = (tid + 512) >> 4,  vr1c = vr0c;
  int kd0 = kr0r * 128 + (kr0c ^ ((kr0r & 7) << 4));
  int kd1 = kr1r * 128 + (kr1c ^ ((kr1r & 7) << 4));
  int vd0 = 16384 + vr0r * 256 + (vr0c ^ ((vr0r & 7) << 4));
  int vd1 = 16384 + vr1r * 256 + (vr1c ^ ((vr1r & 7) << 4));
  const char* KsA = (const char*)Kbh + (size_t)kr0r * 128 + kr0c;  // +16384/tile
  const char* KsB = (const char*)Kbh + (size_t)kr1r * 128 + kr1c;
  const char* VsA = (const char*)Vbh + (size_t)vr0r * (NS * 2) + vr0c;  // +256/tile
  const char* VsB = (const char*)Vbh + (size_t)vr1r * (NS * 2) + vr1c;

  // prologue: stage tile 0 into buffer 0
  *(i32x4*)(lds + kd0) = *(const i32x4*)KsA;
  *(i32x4*)(lds + kd1) = *(const i32x4*)KsB;
  *(i32x4*)(lds + vd0) = *(const i32x4*)VsA;
  *(i32x4*)(lds + vd1) = *(const i32x4*)VsB;

  // ---- hoisted LDS read offsets (buffer-relative)
  int krow = kh * 32 + ql;
  int ksw  = (krow & 7) << 4;
  int kboff[4];
  #pragma unroll
  for (int t = 0; t < 4; ++t) kboff[t] = krow * 128 + ((t * 32 + c * 16) ^ ksw);
  int bvoff[2][2];
  #pragma unroll
  for (int dt = 0; dt < 2; ++dt) {
    int drow = dt * 32 + ql;
    int vsw  = (drow & 7) << 4;
    #pragma unroll
    for (int ks = 0; ks < 2; ++ks)
      bvoff[dt][ks] = 16384 + drow * 256 + ((kh * 64 + ks * 32 + c * 16) ^ vsw);
  }

  i32x4 kA, kB, vA, vB;

  for (int kt = 0; kt < NT; ++kt) {
    __syncthreads();
    if (kt < NT - 1) {
      kA = *(const i32x4*)(KsA + (size_t)(kt + 1) * 16384);
      kB = *(const i32x4*)(KsB + (size_t)(kt + 1) * 16384);
      vA = *(const i32x4*)(VsA + (size_t)(kt + 1) * 256);
      vB = *(const i32x4*)(VsB + (size_t)(kt + 1) * 256);
    }
    char* buf = lds + (kt & 1) * 32768;

    // swapped QK^T: St[key][q] over this wave's 32 keys x 32 q
    bf16x8 ak0 = *(const bf16x8*)(buf + kboff[0]);
    bf16x8 ak1 = *(const bf16x8*)(buf + kboff[1]);
    bf16x8 ak2 = *(const bf16x8*)(buf + kboff[2]);
    bf16x8 ak3 = *(const bf16x8*)(buf + kboff[3]);
    f32x16 s{};
    s = mfma32(ak0, aq[0], s);
    s = mfma32(ak1, aq[1], s);
    s = mfma32(ak2, aq[2], s);
    s = mfma32(ak3, aq[3], s);

    // transform + pack (lane: col q=ql; reg r -> key_local (r&3)+8*(r>>2)+4c)
    int pk[8];
    #pragma unroll
    for (int g = 0; g < 4; ++g) {
      float wq[4];
      #pragma unroll
      for (int j = 0; j < 4; ++j) {
        float x = s[g * 4 + j];
        float a = fminf(fabsf(x), 0.999999f);
        float sq = __builtin_amdgcn_sqrtf(1.0f - a);
        float p = fmaf(fmaf(fmaf(-0.005961377f, a, 0.02363857f), a,
                            -0.06751758f), a, 0.49998939f);   // acos/pi poly
        float u = sq * p;
        float t1 = (x >= 0.0f) ? (1.0f - u) : u;
        float t2 = t1 * t1, t4 = t2 * t2;
        wq[j] = t4 * t4;
      }
      pk[g * 2]     = cvtpk_bf16(wq[0], wq[1]);
      pk[g * 2 + 1] = cvtpk_bf16(wq[2], wq[3]);
    }
    // half-wave exchange -> A-fragments P[q=ql][k_local]
    int xpk[8];
    #pragma unroll
    for (int i = 0; i < 8; ++i) xpk[i] = __shfl_xor(pk[i], 32);
    i32x4 pa0i = c ? (i32x4){xpk[2], xpk[3], pk[2], pk[3]}
                   : (i32x4){pk[0], pk[1], xpk[0], xpk[1]};
    i32x4 pa1i = c ? (i32x4){xpk[6], xpk[7], pk[6], pk[7]}
                   : (i32x4){pk[4], pk[5], xpk[4], xpk[5]};
    bf16x8 pa0 = __builtin_bit_cast(bf16x8, pa0i);
    bf16x8 pa1 = __builtin_bit_cast(bf16x8, pa1i);

    // PV: X[q][d] += P * V^T (keys kh*32 + ks*16 slices)
    bf16x8 bv00 = *(const bf16x8*)(buf + bvoff[0][0]);
    bf16x8 bv10 = *(const bf16x8*)(buf + bvoff[1][0]);
    bf16x8 bv01 = *(const bf16x8*)(buf + bvoff[0][1]);
    bf16x8 bv11 = *(const bf16x8*)(buf + bvoff[1][1]);
    xa0 = mfma32(pa0, bv00, xa0);
    xa1 = mfma32(pa0, bv10, xa1);
    xa0 = mfma32(pa1, bv01, xa0);
    xa1 = mfma32(pa1, bv11, xa1);

    if (kt < NT - 1) {
      char* nb = lds + ((kt + 1) & 1) * 32768;
      *(i32x4*)(nb + kd0) = kA;
      *(i32x4*)(nb + kd1) = kB;
      *(i32x4*)(nb + vd0) = vA;
      *(i32x4*)(nb + vd1) = vB;
    }
  }

  // ---- epilogue: combine 4 kh-partials via LDS, mask, L2-norm, += out
  __syncthreads();   // all waves done reading final tile before cmb overlay
  float (*cmb)[64][64] = (float(*)[64][64])lds;   // [3][64 q][64 d] = 48 KB
  if (kh != 0) {
    #pragma unroll
    for (int r = 0; r < 16; ++r) {
      int qrow = qsub * 32 + (r & 3) + 8 * (r >> 2) + 4 * c;
      cmb[kh - 1][qrow][ql]      = xa0[r];
      cmb[kh - 1][qrow][32 + ql] = xa1[r];
    }
  }
  __syncthreads();
  if (kh == 0) {
    #pragma unroll
    for (int r = 0; r < 16; ++r) {
      int qloc = (r & 3) + 8 * (r >> 2) + 4 * c;
      int qrow = qsub * 32 + qloc;
      int row  = q0 + qrow;
      float m  = mask[b * NS + row];
      float x0 = (xa0[r] + cmb[0][qrow][ql] + cmb[1][qrow][ql] + cmb[2][qrow][ql]) * m;
      float x1 = (xa1[r] + cmb[0][qrow][32 + ql] + cmb[1][qrow][32 + ql] + cmb[2][qrow][32 + ql]) * m;
      float s2 = x0 * x0 + x1 * x1;
      #pragma unroll
      for (int mm = 1; mm < 32; mm <<= 1) s2 += __shfl_xor(s2, mm);
      float sc = rsqrtf(fmaxf(s2, 1e-24f));
      size_t base = ((size_t)bh * NS + row) * ND;
      out[base + ql]      += x0 * sc;
      out[base + 32 + ql] += x1 * sc;
    }
  }
}

// ---------------------------------------------------------------------------
extern "C" void kernel_launch(void* const* d_in, const int* in_sizes, int n_in,
                              void* d_out, int out_size, void* d_ws, size_t ws_size,
                              hipStream_t stream) {
  const float* Q    = (const float*)d_in[0];
  const float* K    = (const float*)d_in[1];
  const float* V    = (const float*)d_in[2];
  const float* mask = (const float*)d_in[3];
  const float* cw   = (const float*)d_in[4];
  float* out = (float*)d_out;

  bf16* Kn  = (bf16*)d_ws;
  bf16* Vmt = Kn + (size_t)BHS * ND;

  prep<<<dim3(NS / 64, BH), 256, 0, stream>>>(K, V, mask, cw, out, Kn, Vmt);
  yoso_attn<<<(NS / 64) * BH, 512, 0, stream>>>(Q, Kn, Vmt, mask, out);
}